// Round 16
// baseline (143.398 us; speedup 1.0000x reference)
//
#include <hip/hip_runtime.h>

// Problem constants
#define S_LEN 2048
#define B_SZ  2
#define F_DIM 1024
#define H_N   16
#define D_DIM 64
#define P_DIM 1024           // H*D
#define M_ROWS 4096          // S*B
#define NBH   32             // B*H

typedef __bf16 bf16x8 __attribute__((ext_vector_type(8)));
typedef __bf16 bf16x4 __attribute__((ext_vector_type(4)));
typedef float  f32x4  __attribute__((ext_vector_type(4)));
typedef unsigned short u16;
typedef unsigned short u16x8 __attribute__((ext_vector_type(8)));
typedef unsigned short u16x4 __attribute__((ext_vector_type(4)));

__device__ __forceinline__ float bf2f(u16 u) {
  union { unsigned int i; float f; } x;
  x.i = ((unsigned int)u) << 16;
  return x.f;
}
__device__ __forceinline__ u16 f2bf(float f) {
  union { float f; unsigned int i; } x;
  x.f = f;
  unsigned int u = x.i;
  u += 0x7fffu + ((u >> 16) & 1u);   // round-to-nearest-even
  return (u16)(u >> 16);
}

// ---------------- f32 -> bf16 convert: all three inputs in one launch ----------
// chunks: src 1048576, w_in 786432, w_out 262144  (f32x4 chunks)
__global__ __launch_bounds__(256) void cvt_all(const float* __restrict__ a,
                                               const float* __restrict__ b,
                                               const float* __restrict__ c_,
                                               u16* __restrict__ oa,
                                               u16* __restrict__ ob,
                                               u16* __restrict__ oc) {
  int i = blockIdx.x * 256 + threadIdx.x;
  const float* in;
  u16* out;
  int off;
  if (i < 1048576)      { in = a;  out = oa; off = i; }
  else if (i < 1835008) { in = b;  out = ob; off = i - 1048576; }
  else                  { in = c_; out = oc; off = i - 1835008; }
  f32x4 v = *reinterpret_cast<const f32x4*>(in + (size_t)off * 4);
  u16x4 o;
  o[0] = f2bf(v[0]); o[1] = f2bf(v[1]); o[2] = f2bf(v[2]); o[3] = f2bf(v[3]);
  *reinterpret_cast<u16x4*>(out + (size_t)off * 4) = o;
}

// ---- async global->LDS stage of a 128x32 bf16 tile (rows have 1024 cols) ----
// 2 global_load_lds (16B) per wave per call.  (out_gemm path)
__device__ __forceinline__ void stage_tile(const u16* __restrict__ gbase,
                                           u16* lds, int row0, int k0,
                                           int wave, int lane) {
  #pragma unroll
  for (int i = 0; i < 2; i++) {
    const u16* g = gbase + ((size_t)(row0 + i * 64 + wave * 16 + (lane >> 2)) << 10)
                 + k0 + (lane & 3) * 8;
    u16* l = lds + (i * 64 + wave * 16) * 32;   // wave-uniform base
    __builtin_amdgcn_global_load_lds(
        (const __attribute__((address_space(1))) void*)(const void*)g,
        (__attribute__((address_space(3))) void*)(void*)l, 16, 0, 0);
  }
}

// ---- async global->LDS stage of a 256x64 bf16 tile (rows have 1024 cols) ----
// 512 threads x 4 chunks of 16B. Chunk XOR-swizzled via pre-swizzled global
// source (m173 pattern): stored chunk cc holds logical chunk cc^(row&7).
__device__ __forceinline__ void stage_tile64(const u16* __restrict__ gbase,
                                             u16* lds, int row0, int k0,
                                             int wave, int tid) {
  #pragma unroll
  for (int i = 0; i < 4; i++) {
    const int chunk = i * 512 + tid;            // 0..2047
    const int row = chunk >> 3;                 // 0..255
    const int scc = (chunk & 7) ^ (row & 7);    // swizzled source chunk
    u16* l = lds + (i * 512 + wave * 64) * 8;   // wave-uniform base
    __builtin_amdgcn_global_load_lds(
        (const __attribute__((address_space(1))) void*)(const void*)
            (gbase + (size_t)(row0 + row) * 1024 + k0 + scc * 8),
        (__attribute__((address_space(3))) void*)(void*)l, 16, 0, 0);
  }
}

// ---------------- QKV projection GEMM: 256x256 tile, BK=64, 8 waves ----------
// 2-buffer K-tile pipeline: stage(kt+1) issued at iteration start, 64 MFMA per
// wave per K-tile (~2500 cyc/SIMD) hide the load latency; single vmcnt(0) +
// barrier per K-tile (drain is amortized 16x better than the 128x32 loop).
// T2 XOR-swizzle on both tiles (BK=64 row stride = 128B would be 16-way
// conflict unswizzled). Wave grid 2Mx4N, per-wave 128x64 output (acc[8][4]).
// Epilogue: q scaled by 0.125*log2(e); which = q/k/v uniform per block.
__global__ __launch_bounds__(512) void qkv_gemm(const u16* __restrict__ A,
                                                const u16* __restrict__ W,
                                                const float* __restrict__ bias,
                                                u16* __restrict__ qw,
                                                u16* __restrict__ kw,
                                                u16* __restrict__ vt) {
  __shared__ u16 As[2][256 * 64];   // 64 KB
  __shared__ u16 Bs[2][256 * 64];   // 64 KB

  const int tid = threadIdx.x;
  const int lane = tid & 63;
  const int wave = tid >> 6;        // 0..7
  const int wr = wave >> 2;         // 0..1 (M half)
  const int wc = wave & 3;          // 0..3 (N quarter)
  const int c = lane & 15;
  const int g = lane >> 4;
  const int sw = c & 7;             // read-side XOR swizzle key

  // XCD-bijective swizzle: 192 blocks = 8 XCDs x 24; consecutive ids share A-panel
  const int bid = blockIdx.x;
  const int id = (bid & 7) * 24 + (bid >> 3);
  const int bm = (id / 12) * 256;
  const int bn = (id % 12) * 256;

  f32x4 acc[8][4];
  #pragma unroll
  for (int mi = 0; mi < 8; mi++)
    #pragma unroll
    for (int ni = 0; ni < 4; ni++) {
      f32x4 z = {0.f, 0.f, 0.f, 0.f};
      acc[mi][ni] = z;
    }

  stage_tile64(A, As[0], bm, 0, wave, tid);
  stage_tile64(W, Bs[0], bn, 0, wave, tid);
  asm volatile("s_waitcnt vmcnt(0)" ::: "memory");
  __builtin_amdgcn_s_barrier();

  int cur = 0;
  for (int kt = 0; kt < 16; kt++) {
    if (kt < 15) {
      stage_tile64(A, As[cur ^ 1], bm, (kt + 1) * 64, wave, tid);
      stage_tile64(W, Bs[cur ^ 1], bn, (kt + 1) * 64, wave, tid);
    }
    // 4 phase-clusters of 16 MFMA (mh x nh quadrants); A-frags read once per mh
    #pragma unroll
    for (int mh = 0; mh < 2; mh++) {
      bf16x8 a[4][2];
      #pragma unroll
      for (int mi = 0; mi < 4; mi++)
        #pragma unroll
        for (int kk = 0; kk < 2; kk++)
          a[mi][kk] = *reinterpret_cast<const bf16x8*>(
              &As[cur][(wr * 128 + (mh * 4 + mi) * 16 + c) * 64 + (((kk * 4 + g) ^ sw) * 8)]);
      #pragma unroll
      for (int nh = 0; nh < 2; nh++) {
        bf16x8 b[2][2];
        #pragma unroll
        for (int ni = 0; ni < 2; ni++)
          #pragma unroll
          for (int kk = 0; kk < 2; kk++)
            b[ni][kk] = *reinterpret_cast<const bf16x8*>(
                &Bs[cur][(wc * 64 + (nh * 2 + ni) * 16 + c) * 64 + (((kk * 4 + g) ^ sw) * 8)]);
        __builtin_amdgcn_s_setprio(1);
        #pragma unroll
        for (int mi = 0; mi < 4; mi++)
          #pragma unroll
          for (int ni = 0; ni < 2; ni++)
            #pragma unroll
            for (int kk = 0; kk < 2; kk++)
              acc[mh * 4 + mi][nh * 2 + ni] = __builtin_amdgcn_mfma_f32_16x16x32_bf16(
                  a[mi][kk], b[ni][kk], acc[mh * 4 + mi][nh * 2 + ni], 0, 0, 0);
        __builtin_amdgcn_s_setprio(0);
      }
    }
    asm volatile("s_waitcnt vmcnt(0)" ::: "memory");
    __builtin_amdgcn_s_barrier();
    cur ^= 1;
  }

  // C/D layout: col = lane&15, row = (lane>>4)*4 + reg   [verified mapping]
  const int which = bn >> 10;       // q/k/v segment, uniform per block
  const float qscale = 0.125f * 1.44269504f;
  #pragma unroll
  for (int ni = 0; ni < 4; ni++) {
    const int p = bn + wc * 64 + ni * 16 + c;
    const float bv = bias[p];
    const int pp = p & 1023;
    const int h = pp >> 6, d = pp & 63;
    #pragma unroll
    for (int mi = 0; mi < 8; mi++) {
      #pragma unroll
      for (int r = 0; r < 4; r++) {
        const int m = bm + wr * 128 + mi * 16 + g * 4 + r;
        const int s = m >> 1, b_ = m & 1;
        const int n = b_ * 16 + h;
        if (which == 0)
          qw[((size_t)n * 2048 + s) * 64 + d] = f2bf((acc[mi][ni][r] + bv) * qscale);
        else if (which == 1)
          kw[((size_t)n * 2048 + s) * 64 + d] = f2bf(acc[mi][ni][r] + bv);
        else
          vt[((size_t)n * 64 + d) * 2048 + s] = f2bf(acc[mi][ni][r] + bv);
      }
    }
  }
}

// ---------------- Output projection GEMM (counted-vmcnt pipeline) ----------------
__global__ __launch_bounds__(256) void out_gemm(const u16* __restrict__ A,
                                                const u16* __restrict__ W,
                                                const float* __restrict__ bias,
                                                float* __restrict__ out) {
  __shared__ u16 As[3][128 * 32];
  __shared__ u16 Bs[3][128 * 32];

  const int lane = threadIdx.x & 63;
  const int wave = threadIdx.x >> 6;
  const int wr = wave >> 1, wc = wave & 1;
  const int bm = blockIdx.y * 128;
  const int bn = blockIdx.x * 128;
  const int c = lane & 15;
  const int g = lane >> 4;

  f32x4 acc[4][4];
  #pragma unroll
  for (int mi = 0; mi < 4; mi++)
    #pragma unroll
    for (int ni = 0; ni < 4; ni++) {
      f32x4 z = {0.f, 0.f, 0.f, 0.f};
      acc[mi][ni] = z;
    }

  stage_tile(A, As[0], bm, 0, wave, lane);
  stage_tile(W, Bs[0], bn, 0, wave, lane);
  stage_tile(A, As[1], bm, 32, wave, lane);
  stage_tile(W, Bs[1], bn, 32, wave, lane);

  int cur = 0;
  for (int kt = 0; kt < 32; kt++) {
    if (kt < 31) asm volatile("s_waitcnt vmcnt(4)" ::: "memory");
    else         asm volatile("s_waitcnt vmcnt(0)" ::: "memory");
    __builtin_amdgcn_s_barrier();
    __builtin_amdgcn_sched_barrier(0);
    if (kt + 2 < 32) {
      int nb = cur + 2; if (nb >= 3) nb -= 3;
      stage_tile(A, As[nb], bm, (kt + 2) * 32, wave, lane);
      stage_tile(W, Bs[nb], bn, (kt + 2) * 32, wave, lane);
    }
    bf16x8 a[4], b[4];
    #pragma unroll
    for (int mi = 0; mi < 4; mi++)
      a[mi] = *reinterpret_cast<const bf16x8*>(&As[cur][(wr * 64 + mi * 16 + c) * 32 + g * 8]);
    #pragma unroll
    for (int ni = 0; ni < 4; ni++)
      b[ni] = *reinterpret_cast<const bf16x8*>(&Bs[cur][(wc * 64 + ni * 16 + c) * 32 + g * 8]);
    __builtin_amdgcn_s_setprio(1);
    #pragma unroll
    for (int mi = 0; mi < 4; mi++)
      #pragma unroll
      for (int ni = 0; ni < 4; ni++)
        acc[mi][ni] = __builtin_amdgcn_mfma_f32_16x16x32_bf16(a[mi], b[ni], acc[mi][ni], 0, 0, 0);
    __builtin_amdgcn_s_setprio(0);
    cur = (cur == 2) ? 0 : cur + 1;
  }

  #pragma unroll
  for (int ni = 0; ni < 4; ni++) {
    const int f = bn + wc * 64 + ni * 16 + c;
    const float bv = bias[f];
    #pragma unroll
    for (int mi = 0; mi < 4; mi++) {
      #pragma unroll
      for (int r = 0; r < 4; r++) {
        const int m = bm + wr * 64 + mi * 16 + g * 4 + r;
        out[(size_t)m * 1024 + f] = acc[mi][ni][r] + bv;
      }
    }
  }
}

// ---- stage one 64x64 bf16 K-tile and one 64x64 V^T-tile into LDS ----
// 512 threads: one 16B chunk per thread per tile; 2 gload_lds per wave per call.
// LDS layout: [64 rows][8 chunks of 16B], chunk XOR-swizzled: stored chunk cc
// holds logical chunk cc^(row&7) (pre-swizzled global source, m173 pattern).
__device__ __forceinline__ void stage_kv(const u16* __restrict__ kb,
                                         const u16* __restrict__ vb,
                                         int ks0, u16* ksbuf, u16* vsbuf,
                                         int wave, int tid) {
  const int row = tid >> 3;
  const int scc = (tid & 7) ^ (row & 7);      // swizzled source chunk
  u16* lk = ksbuf + (wave * 64) * 8;          // wave-uniform base
  u16* lv = vsbuf + (wave * 64) * 8;
  __builtin_amdgcn_global_load_lds(
      (const __attribute__((address_space(1))) void*)(const void*)
          (kb + (size_t)(ks0 + row) * 64 + scc * 8),
      (__attribute__((address_space(3))) void*)(void*)lk, 16, 0, 0);
  __builtin_amdgcn_global_load_lds(
      (const __attribute__((address_space(1))) void*)(const void*)
          (vb + (size_t)row * 2048 + ks0 + scc * 8),
      (__attribute__((address_space(3))) void*)(void*)lv, 16, 0, 0);
}

// ---------------- Flash attention, bf16 MFMA, swapped QK^T (R12 structure) ----
// grid: 512 blocks (XCD-swizzled, 2 blocks/CU resident), 512 thr = 8 waves.
// Block owns 128 q-rows (16/wave); K/V tiles in 3-buffer LDS, 2-deep prefetch,
// one raw barrier per tile, counted vmcnt(2) (T4).
// QK^T swapped (A=K, B=Q): lane holds 16 key-scores for q=lane&15.
// Softmax: P = exp2(s) raw via single v_exp_f32, no reference shift.
__global__ __launch_bounds__(512) void attn_fwd(const u16* __restrict__ qw,
                                                const u16* __restrict__ kw,
                                                const u16* __restrict__ vt,
                                                u16* __restrict__ ao) {
  __shared__ u16 Ks[3][64 * 64];   // [key][d], swizzled chunks
  __shared__ u16 Vs[3][64 * 64];   // [d][key], swizzled chunks
  __shared__ u16 Pl[8][16][76];    // per-wave P buffer, stride 152B (~2-way max)

  const int tid = threadIdx.x;
  const int wave = tid >> 6;
  const int lane = tid & 63;
  const int c = lane & 15;        // frag row/col index
  const int g = lane >> 4;        // k-group within frag
  const int sw = c & 7;           // read-side XOR swizzle key

  // XCD-bijective swizzle: 512 blocks = 8 XCDs x 64; XCD k gets heads [4k,4k+4)
  const int bid = blockIdx.x;
  const int id = (bid & 7) * 64 + (bid >> 3);
  const int n = id >> 4;          // head-batch: n = b*16 + h
  const int qt = id & 15;         // q-tile (128 rows each)
  const int b_ = n >> 4, h = n & 15;
  const int q0 = qt * 128 + wave * 16;

  // Q B-frags (2 k-steps), held for all 32 KV tiles; q pre-scaled (log2 domain)
  bf16x8 qb[2];
  #pragma unroll
  for (int kk = 0; kk < 2; kk++)
    qb[kk] = *reinterpret_cast<const bf16x8*>(
        qw + ((size_t)n * 2048 + q0 + c) * 64 + kk * 32 + g * 8);

  const u16* kb = kw + (size_t)n * 2048 * 64;   // [s][d]
  const u16* vb = vt + (size_t)n * 64 * 2048;   // [d][s]

  f32x4 O[4];                     // [dt]; row g*4+r = q-local, col c -> d
  float l_run = 0.f;              // lane-partial (16 keys/lane)
  #pragma unroll
  for (int dt = 0; dt < 4; dt++) {
    f32x4 z = {0.f, 0.f, 0.f, 0.f};
    O[dt] = z;
  }

  stage_kv(kb, vb, 0,  Ks[0], Vs[0], wave, tid);
  stage_kv(kb, vb, 64, Ks[1], Vs[1], wave, tid);

  int cur = 0;
  for (int kt = 0; kt < 32; kt++) {
    // own stage(kt) done; leave stage(kt+1)'s 2 loads in flight
    if (kt < 31) asm volatile("s_waitcnt vmcnt(2)" ::: "memory");
    else         asm volatile("s_waitcnt vmcnt(0)" ::: "memory");
    __builtin_amdgcn_s_barrier();
    __builtin_amdgcn_sched_barrier(0);
    if (kt + 2 < 32) {
      int nb = cur + 2; if (nb >= 3) nb -= 3;
      stage_kv(kb, vb, (kt + 2) * 64, Ks[nb], Vs[nb], wave, tid);
    }

    // ---- S^T = K Q^T : col=c -> q, row=g*4+r -> key-within-subtile ----
    f32x4 s[4];
    #pragma unroll
    for (int st = 0; st < 4; st++) { f32x4 z = {0.f,0.f,0.f,0.f}; s[st] = z; }
    __builtin_amdgcn_s_setprio(1);
    #pragma unroll
    for (int st = 0; st < 4; st++) {
      #pragma unroll
      for (int kk = 0; kk < 2; kk++) {
        bf16x8 ka = *reinterpret_cast<const bf16x8*>(
            &Ks[cur][(st * 16 + c) * 64 + ((kk * 4 + g) ^ sw) * 8]);
        s[st] = __builtin_amdgcn_mfma_f32_16x16x32_bf16(ka, qb[kk], s[st], 0, 0, 0);
      }
    }
    __builtin_amdgcn_s_setprio(0);

    // ---- softmax: P = exp2(s), single v_exp_f32 per score ----
    float psum = 0.f;
    #pragma unroll
    for (int st = 0; st < 4; st++) {
      const float p0 = __builtin_amdgcn_exp2f(s[st][0]);
      const float p1 = __builtin_amdgcn_exp2f(s[st][1]);
      const float p2 = __builtin_amdgcn_exp2f(s[st][2]);
      const float p3 = __builtin_amdgcn_exp2f(s[st][3]);
      psum += (p0 + p1) + (p2 + p3);
      bf16x4 pk = { (__bf16)p0, (__bf16)p1, (__bf16)p2, (__bf16)p3 };
      *reinterpret_cast<bf16x4*>(&Pl[wave][c][st * 16 + g * 4]) = pk;
    }
    l_run += psum;                // lane-partial; reduced across g after loop

    // ---- O += P V : A=P from LDS, B=V^T rows from swizzled LDS ----
    __builtin_amdgcn_s_setprio(1);
    #pragma unroll
    for (int kk = 0; kk < 2; kk++) {
      bf16x8 pa = *reinterpret_cast<const bf16x8*>(&Pl[wave][c][kk * 32 + g * 8]);
      #pragma unroll
      for (int dt = 0; dt < 4; dt++) {
        bf16x8 vf = *reinterpret_cast<const bf16x8*>(
            &Vs[cur][(dt * 16 + c) * 64 + ((kk * 4 + g) ^ sw) * 8]);
        O[dt] = __builtin_amdgcn_mfma_f32_16x16x32_bf16(pa, vf, O[dt], 0, 0, 0);
      }
    }
    __builtin_amdgcn_s_setprio(0);

    cur = (cur == 2) ? 0 : cur + 1;
  }

  // ---- finish l: reduce lane-partials across g ----
  l_run += __shfl_xor(l_run, 16);
  l_run += __shfl_xor(l_run, 32);

  // ---- epilogue: O/l -> ao bf16 [m = s*2+b][p = h*64+d] ----
  #pragma unroll
  for (int r = 0; r < 4; r++) {
    const float lq = __shfl(l_run, g * 4 + r);
    const float inv = 1.0f / lq;
    const int q = q0 + g * 4 + r;
    const size_t m = (size_t)q * 2 + b_;
    #pragma unroll
    for (int dt = 0; dt < 4; dt++)
      ao[m * 1024 + h * 64 + dt * 16 + c] = f2bf(O[dt][r] * inv);
  }
}

// ---------------- launch ----------------
extern "C" void kernel_launch(void* const* d_in, const int* in_sizes, int n_in,
                              void* d_out, int out_size, void* d_ws, size_t ws_size,
                              hipStream_t stream) {
  const float* src   = (const float*)d_in[0];
  const float* w_in  = (const float*)d_in[1];
  const float* b_in  = (const float*)d_in[2];
  const float* w_out = (const float*)d_in[3];
  const float* b_out = (const float*)d_in[4];
  float* out = (float*)d_out;

  char* ws = (char*)d_ws;
  u16* srcb = (u16*)(ws);                         //  8 MB  src bf16 [4096][1024]
  u16* wib  = (u16*)(ws + ((size_t)8  << 20));    //  6 MB  W_in bf16 [3072][1024]
  u16* wob  = (u16*)(ws + ((size_t)14 << 20));    //  2 MB  W_out bf16 [1024][1024]
  u16* qw   = (u16*)(ws + ((size_t)16 << 20));    //  8 MB  q bf16 [32][2048][64]
  u16* kw   = (u16*)(ws + ((size_t)24 << 20));    //  8 MB  k bf16 [32][2048][64]
  u16* vt   = (u16*)(ws + ((size_t)32 << 20));    //  8 MB  v^T bf16 [32][64][2048]
  u16* ao   = (u16*)(ws + ((size_t)40 << 20));    //  8 MB  attn out bf16 [4096][1024]

  cvt_all<<<8192, 256, 0, stream>>>(src, w_in, w_out, srcb, wib, wob);

  qkv_gemm<<<192, 512, 0, stream>>>(srcb, wib, b_in, qw, kw, vt);
  attn_fwd<<<512, 512, 0, stream>>>(qw, kw, vt, ao);
  out_gemm<<<dim3(8, 32), 256, 0, stream>>>(ao, wob, b_out, out);
}

// Round 17
// 129.395 us; speedup vs baseline: 1.1082x; 1.1082x over previous
//
#include <hip/hip_runtime.h>

// Problem constants
#define S_LEN 2048
#define B_SZ  2
#define F_DIM 1024
#define H_N   16
#define D_DIM 64
#define P_DIM 1024           // H*D
#define M_ROWS 4096          // S*B
#define NBH   32             // B*H

typedef __bf16 bf16x8 __attribute__((ext_vector_type(8)));
typedef __bf16 bf16x4 __attribute__((ext_vector_type(4)));
typedef float  f32x4  __attribute__((ext_vector_type(4)));
typedef float  f32x16 __attribute__((ext_vector_type(16)));
typedef unsigned short u16;
typedef unsigned short u16x8 __attribute__((ext_vector_type(8)));
typedef unsigned short u16x4 __attribute__((ext_vector_type(4)));

__device__ __forceinline__ float bf2f(u16 u) {
  union { unsigned int i; float f; } x;
  x.i = ((unsigned int)u) << 16;
  return x.f;
}
__device__ __forceinline__ u16 f2bf(float f) {
  union { float f; unsigned int i; } x;
  x.f = f;
  unsigned int u = x.i;
  u += 0x7fffu + ((u >> 16) & 1u);   // round-to-nearest-even
  return (u16)(u >> 16);
}

// ---------------- f32 -> bf16 convert: all three inputs in one launch ----------
__global__ __launch_bounds__(256) void cvt_all(const float* __restrict__ a,
                                               const float* __restrict__ b,
                                               const float* __restrict__ c_,
                                               u16* __restrict__ oa,
                                               u16* __restrict__ ob,
                                               u16* __restrict__ oc) {
  int i = blockIdx.x * 256 + threadIdx.x;
  const float* in;
  u16* out;
  int off;
  if (i < 1048576)      { in = a;  out = oa; off = i; }
  else if (i < 1835008) { in = b;  out = ob; off = i - 1048576; }
  else                  { in = c_; out = oc; off = i - 1835008; }
  f32x4 v = *reinterpret_cast<const f32x4*>(in + (size_t)off * 4);
  u16x4 o;
  o[0] = f2bf(v[0]); o[1] = f2bf(v[1]); o[2] = f2bf(v[2]); o[3] = f2bf(v[3]);
  *reinterpret_cast<u16x4*>(out + (size_t)off * 4) = o;
}

// ---- async global->LDS stage of a 128x32 bf16 tile (rows have 1024 cols) ----
__device__ __forceinline__ void stage_tile(const u16* __restrict__ gbase,
                                           u16* lds, int row0, int k0,
                                           int wave, int lane) {
  #pragma unroll
  for (int i = 0; i < 2; i++) {
    const u16* g = gbase + ((size_t)(row0 + i * 64 + wave * 16 + (lane >> 2)) << 10)
                 + k0 + (lane & 3) * 8;
    u16* l = lds + (i * 64 + wave * 16) * 32;   // wave-uniform base
    __builtin_amdgcn_global_load_lds(
        (const __attribute__((address_space(1))) void*)(const void*)g,
        (__attribute__((address_space(3))) void*)(void*)l, 16, 0, 0);
  }
}

// ---------------- QKV projection GEMM (counted-vmcnt pipeline, R12/R14) -------
__global__ __launch_bounds__(256) void qkv_gemm(const u16* __restrict__ A,
                                                const u16* __restrict__ W,
                                                const float* __restrict__ bias,
                                                u16* __restrict__ qw,
                                                u16* __restrict__ kw,
                                                u16* __restrict__ vt) {
  __shared__ u16 As[3][128 * 32];
  __shared__ u16 Bs[3][128 * 32];

  const int lane = threadIdx.x & 63;
  const int wave = threadIdx.x >> 6;
  const int wr = wave >> 1, wc = wave & 1;     // wave grid 2x2
  const int bm = blockIdx.y * 128;
  const int bn = blockIdx.x * 128;
  const int c = lane & 15;
  const int g = lane >> 4;

  f32x4 acc[4][4];
  #pragma unroll
  for (int mi = 0; mi < 4; mi++)
    #pragma unroll
    for (int ni = 0; ni < 4; ni++) {
      f32x4 z = {0.f, 0.f, 0.f, 0.f};
      acc[mi][ni] = z;
    }

  stage_tile(A, As[0], bm, 0, wave, lane);
  stage_tile(W, Bs[0], bn, 0, wave, lane);
  stage_tile(A, As[1], bm, 32, wave, lane);
  stage_tile(W, Bs[1], bn, 32, wave, lane);

  int cur = 0;
  for (int kt = 0; kt < 32; kt++) {
    if (kt < 31) asm volatile("s_waitcnt vmcnt(4)" ::: "memory");
    else         asm volatile("s_waitcnt vmcnt(0)" ::: "memory");
    __builtin_amdgcn_s_barrier();
    __builtin_amdgcn_sched_barrier(0);
    if (kt + 2 < 32) {
      int nb = cur + 2; if (nb >= 3) nb -= 3;
      stage_tile(A, As[nb], bm, (kt + 2) * 32, wave, lane);
      stage_tile(W, Bs[nb], bn, (kt + 2) * 32, wave, lane);
    }
    bf16x8 a[4], b[4];
    #pragma unroll
    for (int mi = 0; mi < 4; mi++)
      a[mi] = *reinterpret_cast<const bf16x8*>(&As[cur][(wr * 64 + mi * 16 + c) * 32 + g * 8]);
    #pragma unroll
    for (int ni = 0; ni < 4; ni++)
      b[ni] = *reinterpret_cast<const bf16x8*>(&Bs[cur][(wc * 64 + ni * 16 + c) * 32 + g * 8]);
    __builtin_amdgcn_s_setprio(1);
    #pragma unroll
    for (int mi = 0; mi < 4; mi++)
      #pragma unroll
      for (int ni = 0; ni < 4; ni++)
        acc[mi][ni] = __builtin_amdgcn_mfma_f32_16x16x32_bf16(a[mi], b[ni], acc[mi][ni], 0, 0, 0);
    __builtin_amdgcn_s_setprio(0);
    cur = (cur == 2) ? 0 : cur + 1;
  }

  // C/D layout: col = lane&15, row = (lane>>4)*4 + reg   [verified mapping]
  const int which = bn >> 10;       // q/k/v segment, uniform per block
  const float qscale = 0.125f * 1.44269504f;
  #pragma unroll
  for (int ni = 0; ni < 4; ni++) {
    const int p = bn + wc * 64 + ni * 16 + c;
    const float bv = bias[p];
    const int pp = p & 1023;
    const int h = pp >> 6, d = pp & 63;
    #pragma unroll
    for (int mi = 0; mi < 4; mi++) {
      #pragma unroll
      for (int r = 0; r < 4; r++) {
        const int m = bm + wr * 64 + mi * 16 + g * 4 + r;
        const int s = m >> 1, b_ = m & 1;
        const int n = b_ * 16 + h;
        if (which == 0)
          qw[((size_t)n * 2048 + s) * 64 + d] = f2bf((acc[mi][ni][r] + bv) * qscale);
        else if (which == 1)
          kw[((size_t)n * 2048 + s) * 64 + d] = f2bf(acc[mi][ni][r] + bv);
        else
          vt[((size_t)n * 64 + d) * 2048 + s] = f2bf(acc[mi][ni][r] + bv);
      }
    }
  }
}

// ---------------- Output projection GEMM (counted-vmcnt pipeline) ----------------
__global__ __launch_bounds__(256) void out_gemm(const u16* __restrict__ A,
                                                const u16* __restrict__ W,
                                                const float* __restrict__ bias,
                                                float* __restrict__ out) {
  __shared__ u16 As[3][128 * 32];
  __shared__ u16 Bs[3][128 * 32];

  const int lane = threadIdx.x & 63;
  const int wave = threadIdx.x >> 6;
  const int wr = wave >> 1, wc = wave & 1;
  const int bm = blockIdx.y * 128;
  const int bn = blockIdx.x * 128;
  const int c = lane & 15;
  const int g = lane >> 4;

  f32x4 acc[4][4];
  #pragma unroll
  for (int mi = 0; mi < 4; mi++)
    #pragma unroll
    for (int ni = 0; ni < 4; ni++) {
      f32x4 z = {0.f, 0.f, 0.f, 0.f};
      acc[mi][ni] = z;
    }

  stage_tile(A, As[0], bm, 0, wave, lane);
  stage_tile(W, Bs[0], bn, 0, wave, lane);
  stage_tile(A, As[1], bm, 32, wave, lane);
  stage_tile(W, Bs[1], bn, 32, wave, lane);

  int cur = 0;
  for (int kt = 0; kt < 32; kt++) {
    if (kt < 31) asm volatile("s_waitcnt vmcnt(4)" ::: "memory");
    else         asm volatile("s_waitcnt vmcnt(0)" ::: "memory");
    __builtin_amdgcn_s_barrier();
    __builtin_amdgcn_sched_barrier(0);
    if (kt + 2 < 32) {
      int nb = cur + 2; if (nb >= 3) nb -= 3;
      stage_tile(A, As[nb], bm, (kt + 2) * 32, wave, lane);
      stage_tile(W, Bs[nb], bn, (kt + 2) * 32, wave, lane);
    }
    bf16x8 a[4], b[4];
    #pragma unroll
    for (int mi = 0; mi < 4; mi++)
      a[mi] = *reinterpret_cast<const bf16x8*>(&As[cur][(wr * 64 + mi * 16 + c) * 32 + g * 8]);
    #pragma unroll
    for (int ni = 0; ni < 4; ni++)
      b[ni] = *reinterpret_cast<const bf16x8*>(&Bs[cur][(wc * 64 + ni * 16 + c) * 32 + g * 8]);
    __builtin_amdgcn_s_setprio(1);
    #pragma unroll
    for (int mi = 0; mi < 4; mi++)
      #pragma unroll
      for (int ni = 0; ni < 4; ni++)
        acc[mi][ni] = __builtin_amdgcn_mfma_f32_16x16x32_bf16(a[mi], b[ni], acc[mi][ni], 0, 0, 0);
    __builtin_amdgcn_s_setprio(0);
    cur = (cur == 2) ? 0 : cur + 1;
  }

  #pragma unroll
  for (int ni = 0; ni < 4; ni++) {
    const int f = bn + wc * 64 + ni * 16 + c;
    const float bv = bias[f];
    #pragma unroll
    for (int mi = 0; mi < 4; mi++) {
      #pragma unroll
      for (int r = 0; r < 4; r++) {
        const int m = bm + wr * 64 + mi * 16 + g * 4 + r;
        out[(size_t)m * 1024 + f] = acc[mi][ni][r] + bv;
      }
    }
  }
}

// ---- stage one 64x64 bf16 K-tile and one 64x64 V^T-tile into LDS ----
// 256 threads: two 16B chunks per thread per tile (4 gload_lds per thread).
// LDS layout: [64 rows][8 chunks of 16B], chunk XOR-swizzled: stored chunk cc
// holds logical chunk cc^(row&7) (pre-swizzled global source, m173 pattern).
__device__ __forceinline__ void stage_kv(const u16* __restrict__ kb,
                                         const u16* __restrict__ vb,
                                         int ks0, u16* ksbuf, u16* vsbuf,
                                         int wave, int tid) {
  #pragma unroll
  for (int i = 0; i < 2; i++) {
    const int chunk = i * 256 + tid;          // 0..511
    const int row = chunk >> 3;
    const int scc = (chunk & 7) ^ (row & 7);  // swizzled source chunk
    u16* lk = ksbuf + (i * 256 + wave * 64) * 8;   // wave-uniform base
    u16* lv = vsbuf + (i * 256 + wave * 64) * 8;
    __builtin_amdgcn_global_load_lds(
        (const __attribute__((address_space(1))) void*)(const void*)
            (kb + (size_t)(ks0 + row) * 64 + scc * 8),
        (__attribute__((address_space(3))) void*)(void*)lk, 16, 0, 0);
    __builtin_amdgcn_global_load_lds(
        (const __attribute__((address_space(1))) void*)(const void*)
            (vb + (size_t)row * 2048 + ks0 + scc * 8),
        (__attribute__((address_space(3))) void*)(void*)lv, 16, 0, 0);
  }
}

// ---------------- Flash attention: 32x32 MFMA, swapped QK^T, in-register P ----
// grid: 512 blocks (XCD-swizzled, 2 blocks/CU), 256 thr = 4 waves, 32 q/wave.
// QK^T: mfma_32x32x16(A=K, B=Q) -> D col=lane&31=q, row=key=(reg&3)+8*(reg>>2)
// +4*(lane>>5)  [m74/m101-verified C/D mapping].
// P stays in registers: 8 v_cvt_pk_bf16_f32 + 4 v_permlane32_swap_b32 per
// key-half re-partition the 16 key-scores across the hi-halves into the PV
// A-frag layout (row=q=lane&31, k=key=8*hi+j). No P LDS traffic at all.
// Softmax: P = exp2(s) raw (fixed-reference, order-free).
// K/V: 3-buffer LDS, 2-deep prefetch, counted vmcnt(4), XOR-swizzled chunks.
__global__ __launch_bounds__(256) void attn_fwd(const u16* __restrict__ qw,
                                                const u16* __restrict__ kw,
                                                const u16* __restrict__ vt,
                                                u16* __restrict__ ao) {
  __shared__ u16 Ks[3][64 * 64];   // [key][d], swizzled chunks
  __shared__ u16 Vs[3][64 * 64];   // [d][key], swizzled chunks

  const int tid = threadIdx.x;
  const int wave = tid >> 6;
  const int lane = tid & 63;
  const int qc = lane & 31;       // q within wave (QK) / d row (PV) / A-B row
  const int hi = lane >> 5;

  // XCD-bijective swizzle: 512 blocks = 8 XCDs x 64
  const int bid = blockIdx.x;
  const int id = (bid & 7) * 64 + (bid >> 3);
  const int n = id >> 4;          // head-batch: n = b*16 + h
  const int qt = id & 15;         // q-tile (128 rows each)
  const int b_ = n >> 4, h = n & 15;
  const int q0 = qt * 128 + wave * 32;

  // Q B-frags (4 k-steps of 16); q pre-scaled (log2 domain)
  bf16x8 qb[4];
  #pragma unroll
  for (int ks = 0; ks < 4; ks++)
    qb[ks] = *reinterpret_cast<const bf16x8*>(
        qw + ((size_t)n * 2048 + q0 + qc) * 64 + ks * 16 + hi * 8);

  const u16* kb = kw + (size_t)n * 2048 * 64;   // [s][d]
  const u16* vb = vt + (size_t)n * 64 * 2048;   // [d][s]

  f32x16 O[2];                    // [d-half]; row=q, col=lane&31 -> d
  #pragma unroll
  for (int dh = 0; dh < 2; dh++)
    #pragma unroll
    for (int r = 0; r < 16; r++) O[dh][r] = 0.f;
  float l_run = 0.f;              // lane-partial (32 of 64 keys for q=qc)

  stage_kv(kb, vb, 0,  Ks[0], Vs[0], wave, tid);
  stage_kv(kb, vb, 64, Ks[1], Vs[1], wave, tid);

  int cur = 0;
  for (int kt = 0; kt < 32; kt++) {
    if (kt < 31) asm volatile("s_waitcnt vmcnt(4)" ::: "memory");
    else         asm volatile("s_waitcnt vmcnt(0)" ::: "memory");
    __builtin_amdgcn_s_barrier();
    __builtin_amdgcn_sched_barrier(0);
    if (kt + 2 < 32) {
      int nb = cur + 2; if (nb >= 3) nb -= 3;
      stage_kv(kb, vb, (kt + 2) * 64, Ks[nb], Vs[nb], wave, tid);
    }

    #pragma unroll
    for (int kh = 0; kh < 2; kh++) {
      // ---- S^T(keys kh*32..+31) = K Q^T ----
      f32x16 s;
      #pragma unroll
      for (int r = 0; r < 16; r++) s[r] = 0.f;
      const int krow = kh * 32 + qc;
      __builtin_amdgcn_s_setprio(1);
      #pragma unroll
      for (int ks = 0; ks < 4; ks++) {
        bf16x8 ka = *reinterpret_cast<const bf16x8*>(
            &Ks[cur][krow * 64 + (((ks * 2 + hi) ^ (qc & 7)) * 8)]);
        s = __builtin_amdgcn_mfma_f32_32x32x16_bf16(ka, qb[ks], s, 0, 0, 0);
      }
      __builtin_amdgcn_s_setprio(0);

      // ---- softmax: p = exp2(s); lane-partial l ----
      float p[16];
      float psum = 0.f;
      #pragma unroll
      for (int r = 0; r < 16; r++) { p[r] = __builtin_amdgcn_exp2f(s[r]); psum += p[r]; }
      l_run += psum;

      // ---- pack + permlane re-partition -> PV A-frags (in registers) ----
      unsigned u[8];
      #pragma unroll
      for (int r1 = 0; r1 < 4; r1++) {
        asm("v_cvt_pk_bf16_f32 %0, %1, %2" : "=v"(u[2 * r1])     : "v"(p[4 * r1 + 0]), "v"(p[4 * r1 + 1]));
        asm("v_cvt_pk_bf16_f32 %0, %1, %2" : "=v"(u[2 * r1 + 1]) : "v"(p[4 * r1 + 2]), "v"(p[4 * r1 + 3]));
      }
      asm("v_permlane32_swap_b32 %0, %1" : "+v"(u[0]), "+v"(u[2]));
      asm("v_permlane32_swap_b32 %0, %1" : "+v"(u[1]), "+v"(u[3]));
      asm("v_permlane32_swap_b32 %0, %1" : "+v"(u[4]), "+v"(u[6]));
      asm("v_permlane32_swap_b32 %0, %1" : "+v"(u[5]), "+v"(u[7]));
      union AF { unsigned w[4]; bf16x8 v; };
      AF af0, af1;
      af0.w[0] = u[0]; af0.w[1] = u[1]; af0.w[2] = u[2]; af0.w[3] = u[3];
      af1.w[0] = u[4]; af1.w[1] = u[5]; af1.w[2] = u[6]; af1.w[3] = u[7];

      // ---- O += P V : A=P (regs), B=V^T rows from swizzled LDS ----
      __builtin_amdgcn_s_setprio(1);
      #pragma unroll
      for (int ks2 = 0; ks2 < 2; ks2++) {
        #pragma unroll
        for (int dh = 0; dh < 2; dh++) {
          const int dr = dh * 32 + qc;
          bf16x8 vf = *reinterpret_cast<const bf16x8*>(
              &Vs[cur][dr * 64 + ((((kh * 2 + ks2) * 2 + hi) ^ (qc & 7)) * 8)]);
          O[dh] = __builtin_amdgcn_mfma_f32_32x32x16_bf16(ks2 ? af1.v : af0.v, vf, O[dh], 0, 0, 0);
        }
      }
      __builtin_amdgcn_s_setprio(0);
    }

    cur = (cur == 2) ? 0 : cur + 1;
  }

  // ---- finish l: combine the two hi-halves ----
  l_run += __shfl_xor(l_run, 32);

  // ---- epilogue: O/l -> ao bf16 [m = s*2+b][p = h*64+d] ----
  float inv16[16];
  #pragma unroll
  for (int r = 0; r < 16; r++) {
    const int qrow = (r & 3) + 8 * (r >> 2) + 4 * hi;
    inv16[r] = 1.0f / __shfl(l_run, qrow);
  }
  #pragma unroll
  for (int dh = 0; dh < 2; dh++) {
    #pragma unroll
    for (int r = 0; r < 16; r++) {
      const int qrow = (r & 3) + 8 * (r >> 2) + 4 * hi;
      const int q = q0 + qrow;
      const size_t m = (size_t)q * 2 + b_;
      ao[m * 1024 + h * 64 + dh * 32 + qc] = f2bf(O[dh][r] * inv16[r]);
    }
  }
}

// ---------------- launch ----------------
extern "C" void kernel_launch(void* const* d_in, const int* in_sizes, int n_in,
                              void* d_out, int out_size, void* d_ws, size_t ws_size,
                              hipStream_t stream) {
  const float* src   = (const float*)d_in[0];
  const float* w_in  = (const float*)d_in[1];
  const float* b_in  = (const float*)d_in[2];
  const float* w_out = (const float*)d_in[3];
  const float* b_out = (const float*)d_in[4];
  float* out = (float*)d_out;

  char* ws = (char*)d_ws;
  u16* srcb = (u16*)(ws);                         //  8 MB  src bf16 [4096][1024]
  u16* wib  = (u16*)(ws + ((size_t)8  << 20));    //  6 MB  W_in bf16 [3072][1024]
  u16* wob  = (u16*)(ws + ((size_t)14 << 20));    //  2 MB  W_out bf16 [1024][1024]
  u16* qw   = (u16*)(ws + ((size_t)16 << 20));    //  8 MB  q bf16 [32][2048][64]
  u16* kw   = (u16*)(ws + ((size_t)24 << 20));    //  8 MB  k bf16 [32][2048][64]
  u16* vt   = (u16*)(ws + ((size_t)32 << 20));    //  8 MB  v^T bf16 [32][64][2048]
  u16* ao   = (u16*)(ws + ((size_t)40 << 20));    //  8 MB  attn out bf16 [4096][1024]

  cvt_all<<<8192, 256, 0, stream>>>(src, w_in, w_out, srcb, wib, wob);

  qkv_gemm<<<dim3(24, 32), 256, 0, stream>>>(srcb, wib, b_in, qw, kw, vt);
  attn_fwd<<<512, 256, 0, stream>>>(qw, kw, vt, ao);
  out_gemm<<<dim3(8, 32), 256, 0, stream>>>(ao, wob, b_out, out);
}